// Round 11
// baseline (547.247 us; speedup 1.0000x reference)
//
#include <hip/hip_runtime.h>
#include <hip/hip_bf16.h>

// GCN forward: 3 layers, N=100000, HIDDEN=128, E=600000.
// Aggregation is linear => aggregate first (A_norm * x), then GEMM by W.
// CSR (pull) built per launch via counting sort; no per-layer atomics.
// Round-11: fusion reverted (occupancy loss hurt the latency-bound gather).
// GEMM replaced by split-bf16 MFMA (16x16x32): x=xh+xl, W=Wh+Wl bf16;
// acc = xh@Wh + xh@Wl + xl@Wh in fp32 -> ~fp32 accuracy at MFMA rate.
// Agg epilogue emits yh/yl bf16 planes (same write bytes as fp32).
// Agg gather body = exact round-9 shape (manual multi-gather bodies kill the
// container, 5/5 — do not reintroduce).

#define HID 128

typedef __attribute__((ext_vector_type(8))) short short8;     // 8 bf16 (A/B frag)
typedef __attribute__((ext_vector_type(4))) float floatx4;    // C/D frag

// ---------- preprocessing ----------

__global__ void k_init_cnt(int* cnt, int n) {
    int i = blockIdx.x * blockDim.x + threadIdx.x;
    if (i < n) cnt[i] = 1;  // self-loop
}

__global__ void k_count_edges(const int* __restrict__ ei, int* cnt, int E) {
    int e = blockIdx.x * blockDim.x + threadIdx.x;
    if (e < E) atomicAdd(&cnt[ei[E + e]], 1);   // dst = ei[E+e]
}

// chunk sums: CHUNK=1024 (256 thr x 4)
__global__ void k_scanA(const int* __restrict__ cnt, int* csum, int n) {
    __shared__ int sd[256];
    int t = threadIdx.x;
    int base = blockIdx.x * 1024 + t * 4;
    int s = 0;
#pragma unroll
    for (int j = 0; j < 4; j++) { int i = base + j; if (i < n) s += cnt[i]; }
    sd[t] = s; __syncthreads();
    for (int off = 128; off > 0; off >>= 1) {
        if (t < off) sd[t] += sd[t + off];
        __syncthreads();
    }
    if (t == 0) csum[blockIdx.x] = sd[0];
}

// parallel exclusive scan over up to 256 chunk sums (NCHUNK=98 here), 1 block
__global__ void k_scanB(int* csum, int* offsets, int nchunk, int n) {
    __shared__ int sd[256];
    int t = threadIdx.x;
    int v = (t < nchunk) ? csum[t] : 0;
    sd[t] = v; __syncthreads();
    for (int off = 1; off < 256; off <<= 1) {
        int u = (t >= off) ? sd[t - off] : 0;
        __syncthreads();
        sd[t] += u;
        __syncthreads();
    }
    if (t < nchunk) csum[t] = sd[t] - v;   // exclusive prefix
    if (t == 0) offsets[n] = sd[255];      // total = E + N
}

// scanC + node_init fused: writes offsets, dinv, cursor, and the self-loop entry.
__global__ void k_scanC(const int* __restrict__ cnt, const int* __restrict__ csum,
                        int* offsets, int* cursor, float* dinv,
                        int* adj_src, float* adj_norm, int n) {
    __shared__ int sd[256];
    int t = threadIdx.x;
    int base = blockIdx.x * 1024 + t * 4;
    int c[4]; int s = 0;
#pragma unroll
    for (int j = 0; j < 4; j++) {
        c[j] = (base + j < n) ? cnt[base + j] : 0;
        s += c[j];
    }
    sd[t] = s; __syncthreads();
    for (int off = 1; off < 256; off <<= 1) {
        int v = (t >= off) ? sd[t - off] : 0;
        __syncthreads();
        sd[t] += v;
        __syncthreads();
    }
    int run = sd[t] - s + csum[blockIdx.x];  // exclusive prefix + chunk base
#pragma unroll
    for (int j = 0; j < 4; j++) {
        int i = base + j;
        if (i < n) {
            offsets[i] = run;
            float di = rsqrtf((float)c[j]);   // deg >= 1 (self-loop)
            dinv[i] = di;
            cursor[i] = run + 1;
            adj_src[run] = i;                 // self-loop entry first
            adj_norm[run] = di * di;
        }
        run += c[j];
    }
}

__global__ void k_fill_edges(const int* __restrict__ ei, int* cursor,
                             const float* __restrict__ dinv,
                             int* adj_src, float* adj_norm, int E) {
    int e = blockIdx.x * blockDim.x + threadIdx.x;
    if (e >= E) return;
    int s = ei[e];
    int d = ei[E + e];
    int pos = atomicAdd(&cursor[d], 1);
    adj_src[pos] = s;
    adj_norm[pos] = dinv[s] * dinv[d];
}

// pack W[l] (fp32 [k][n]) into transposed bf16 planes Whp/Wlp [n][k]
__global__ void k_packW(const float* __restrict__ Ws, ushort* Whp, ushort* Wlp,
                        int nlayers) {
    int idx = blockIdx.x * blockDim.x + threadIdx.x;      // l*16384 + n*128 + k
    if (idx >= nlayers * HID * HID) return;
    int l = idx >> 14;
    int n = (idx >> 7) & 127;
    int k = idx & 127;
    float w = Ws[(size_t)l * HID * HID + k * HID + n];
    __hip_bfloat16 hi = __float2bfloat16(w);
    float lo = w - __bfloat162float(hi);
    __hip_bfloat16 lo16 = __float2bfloat16(lo);
    Whp[idx] = *(ushort*)&hi;
    Wlp[idx] = *(ushort*)&lo16;
}

// ---------- per-layer: pull aggregation ----------
// One wave per node. Wave quarters: q>>1 = edge-slot parity, q&1 = feature half.
// Body = round-9 verified shape. Epilogue: split acc into bf16 hi/lo planes.

__global__ __launch_bounds__(256) void k_agg(const float* __restrict__ x,
                                             const int* __restrict__ offsets,
                                             const int* __restrict__ adj_src,
                                             const float* __restrict__ adj_norm,
                                             ushort* __restrict__ yh,
                                             ushort* __restrict__ yl, int n) {
    int gid = blockIdx.x * blockDim.x + threadIdx.x;
    int node = gid >> 6;
    int lane = gid & 63;
    if (node >= n) return;
    int beg = offsets[node];
    int end = offsets[node + 1];
    int q    = lane >> 4;            // quarter 0..3
    int ql   = lane & 15;
    int f4   = (q & 1) * 16 + ql;    // float4 index within row, [0,32)
    int epar = q >> 1;               // edge-slot parity 0/1
    float4 acc = {0.f, 0.f, 0.f, 0.f};
#pragma unroll 2
    for (int e = beg; e < end; e += 2) {
        int me = e + epar;
        int mc = me < end ? me : end - 1;          // clamp -> always-valid load
        int s  = adj_src[mc];                      // broadcast within quarter-pair
        float w = me < end ? adj_norm[mc] : 0.f;   // masked weight for odd tail
        float4 v = ((const float4*)(x + (size_t)s * HID))[f4];
        acc.x += w * v.x;
        acc.y += w * v.y;
        acc.z += w * v.z;
        acc.w += w * v.w;
    }
    acc.x += __shfl_xor(acc.x, 32);
    acc.y += __shfl_xor(acc.y, 32);
    acc.z += __shfl_xor(acc.z, 32);
    acc.w += __shfl_xor(acc.w, 32);
    if (lane < 32) {
        float a[4] = {acc.x, acc.y, acc.z, acc.w};
        ushort4 h, l;
        ushort* hp = (ushort*)&h;
        ushort* lp = (ushort*)&l;
#pragma unroll
        for (int j = 0; j < 4; j++) {
            __hip_bfloat16 hi = __float2bfloat16(a[j]);
            float lo = a[j] - __bfloat162float(hi);
            __hip_bfloat16 lo16 = __float2bfloat16(lo);
            hp[j] = *(ushort*)&hi;
            lp[j] = *(ushort*)&lo16;
        }
        ((ushort4*)(yh + (size_t)node * HID))[lane] = h;
        ((ushort4*)(yl + (size_t)node * HID))[lane] = l;
    }
}

// ---------- per-layer: GEMM via split-bf16 MFMA 16x16x32 ----------
// Block 256 thr = 4 waves; tile 64 rows x 128 cols; wave w -> rows w*16..w*16+15.
// A frag: A[m=lane&15][k=(lane>>4)*8+j] -> 16B contiguous from yh/yl row-major.
// B frag: B[k=(lane>>4)*8+j][n=lane&15] -> 16B contiguous from Whp/Wlp [n][k].
// C/D: col=lane&15, row=(lane>>4)*4+reg (measured m89 mapping).
// acc = Ah@Bh + Ah@Bl + Al@Bh  (fp32 accumulate; dropped Al@Bl ~2^-16).

__global__ __launch_bounds__(256) void k_gemm_mfma(const ushort* __restrict__ yh,
                                                   const ushort* __restrict__ yl,
                                                   const ushort* __restrict__ Whp,
                                                   const ushort* __restrict__ Wlp,
                                                   const float* __restrict__ bias,
                                                   float* __restrict__ out, int n) {
    int t = threadIdx.x;
    int wave = t >> 6;
    int lane = t & 63;
    int m16  = lane & 15;
    int oct  = lane >> 4;            // k-octet 0..3

    int rowA = blockIdx.x * 64 + wave * 16 + m16;       // A-operand row for this lane
    const ushort* ah_base = yh + (size_t)rowA * HID + oct * 8;
    const ushort* al_base = yl + (size_t)rowA * HID + oct * 8;

    floatx4 acc[8];
#pragma unroll
    for (int c = 0; c < 8; c++) acc[c] = (floatx4){0.f, 0.f, 0.f, 0.f};

#pragma unroll
    for (int ks = 0; ks < 4; ks++) {                    // K = 128 = 4 x 32
        short8 ah = *(const short8*)(ah_base + ks * 32);
        short8 al = *(const short8*)(al_base + ks * 32);
#pragma unroll
        for (int c = 0; c < 8; c++) {                   // 8 col-tiles of 16
            const ushort* bp = Whp + (size_t)(c * 16 + m16) * HID + ks * 32 + oct * 8;
            const ushort* bq = Wlp + (size_t)(c * 16 + m16) * HID + ks * 32 + oct * 8;
            short8 bh = *(const short8*)bp;
            short8 bl = *(const short8*)bq;
            acc[c] = __builtin_amdgcn_mfma_f32_16x16x32_bf16(ah, bh, acc[c], 0, 0, 0);
            acc[c] = __builtin_amdgcn_mfma_f32_16x16x32_bf16(ah, bl, acc[c], 0, 0, 0);
            acc[c] = __builtin_amdgcn_mfma_f32_16x16x32_bf16(al, bh, acc[c], 0, 0, 0);
        }
    }

    // epilogue: bias + relu + store (C/D: col=lane&15, row=(lane>>4)*4+reg)
    int rowbase = blockIdx.x * 64 + wave * 16 + oct * 4;
#pragma unroll
    for (int c = 0; c < 8; c++) {
        int col = c * 16 + m16;
        float b = bias[col];
#pragma unroll
        for (int r = 0; r < 4; r++) {
            int row = rowbase + r;
            if (row < n) {
                float v = fmaxf(acc[c][r] + b, 0.f);
                out[(size_t)row * HID + col] = v;
            }
        }
    }
}

// ---------- launch ----------

extern "C" void kernel_launch(void* const* d_in, const int* in_sizes, int n_in,
                              void* d_out, int out_size, void* d_ws, size_t ws_size,
                              hipStream_t stream) {
    const int* ei = (const int*)d_in[0];          // (2, E) int32
    const float* emb = (const float*)d_in[1];     // (N, 128)
    const float* Ws = (const float*)d_in[2];      // (3, 128, 128)
    const float* bs = (const float*)d_in[3];      // (3, 128)

    const int E = in_sizes[0] / 2;                // 600000
    const int N = in_sizes[1] / HID;              // 100000
    const int NL = in_sizes[3] / HID;             // 3
    const int TOT = E + N;
    const int NPAD = ((N + 63) / 64) * 64;        // 100032 (A-loads unmasked)

    // workspace carve-up (256B aligned)
    char* p = (char*)d_ws;
    auto carve = [&](size_t bytes) {
        char* r = p;
        p += (bytes + 255) & ~(size_t)255;
        return (void*)r;
    };
    int*    cnt      = (int*)   carve((size_t)N * 4);
    int*    offsets  = (int*)   carve((size_t)(N + 1) * 4);
    int*    cursor   = (int*)   carve((size_t)N * 4);
    float*  dinv     = (float*) carve((size_t)N * 4);
    int*    csum     = (int*)   carve(1024 * 4);
    int*    adj_src  = (int*)   carve((size_t)TOT * 4);
    float*  adj_norm = (float*) carve((size_t)TOT * 4);
    ushort* yh       = (ushort*)carve((size_t)NPAD * HID * 2);
    ushort* yl       = (ushort*)carve((size_t)NPAD * HID * 2);
    ushort* Whp      = (ushort*)carve((size_t)NL * HID * HID * 2);
    ushort* Wlp      = (ushort*)carve((size_t)NL * HID * HID * 2);
    float*  xbufA    = (float*) carve((size_t)N * HID * 4);
    float*  xbufB    = (float*) d_out;    // l0 and l2 outputs land here

    const int NCHUNK = (N + 1023) / 1024;   // 98 <= 256 (scanB capacity)

    k_init_cnt<<<(N + 255) / 256, 256, 0, stream>>>(cnt, N);
    k_count_edges<<<(E + 255) / 256, 256, 0, stream>>>(ei, cnt, E);
    k_scanA<<<NCHUNK, 256, 0, stream>>>(cnt, csum, N);
    k_scanB<<<1, 256, 0, stream>>>(csum, offsets, NCHUNK, N);
    k_scanC<<<NCHUNK, 256, 0, stream>>>(cnt, csum, offsets, cursor, dinv,
                                        adj_src, adj_norm, N);
    k_fill_edges<<<(E + 255) / 256, 256, 0, stream>>>(ei, cursor, dinv,
                                                      adj_src, adj_norm, E);
    k_packW<<<(NL * HID * HID + 255) / 256, 256, 0, stream>>>(Ws, Whp, Wlp, NL);

    const int aggBlocks = (N * 64 + 255) / 256;
    const int gemmBlocks = NPAD / 64;     // 1563
    // l0: emb -> d_out, l1: d_out -> xbufA, l2: xbufA -> d_out
    const float* x = emb;
    for (int l = 0; l < NL; l++) {
        float* o = (l == 1) ? xbufA : xbufB;
        k_agg<<<aggBlocks, 256, 0, stream>>>(x, offsets, adj_src, adj_norm, yh, yl, N);
        k_gemm_mfma<<<gemmBlocks, 256, 0, stream>>>(yh, yl,
                                                    Whp + (size_t)l * HID * HID,
                                                    Wlp + (size_t)l * HID * HID,
                                                    bs + (size_t)l * HID, o, N);
        x = o;
    }
}

// Round 12
// 432.478 us; speedup vs baseline: 1.2654x; 1.2654x over previous
//
#include <hip/hip_runtime.h>
#include <hip/hip_bf16.h>

// GCN forward: 3 layers, N=100000, HIDDEN=128, E=600000.
// Aggregation is linear => aggregate first (A_norm * x), then GEMM by W.
// CSR (pull) built per launch via counting sort; no per-layer atomics.
// Round-12: MFMA GEMM now stages W planes in LDS (round-11 read B frags from
// global in the inner loop -> latency-bound, MfmaUtil 4.5%). Math identical to
// round-11 (verified absmax 3.9e-3): split-bf16, acc = Ah@Bh + Ah@Bl + Al@Bh.
// Agg gather body = round-9 verified shape (manual multi-gather bodies kill the
// container, 5/5 — do not reintroduce).

#define HID 128

typedef __attribute__((ext_vector_type(8))) short short8;     // 8 bf16 (A/B frag)
typedef __attribute__((ext_vector_type(4))) float floatx4;    // C/D frag

#define WLDS 136   // padded row stride (ushorts): 272 B -> balanced LDS banks

// ---------- preprocessing ----------

__global__ void k_init_cnt(int* cnt, int n) {
    int i = blockIdx.x * blockDim.x + threadIdx.x;
    if (i < n) cnt[i] = 1;  // self-loop
}

__global__ void k_count_edges(const int* __restrict__ ei, int* cnt, int E) {
    int e = blockIdx.x * blockDim.x + threadIdx.x;
    if (e < E) atomicAdd(&cnt[ei[E + e]], 1);   // dst = ei[E+e]
}

// chunk sums: CHUNK=1024 (256 thr x 4)
__global__ void k_scanA(const int* __restrict__ cnt, int* csum, int n) {
    __shared__ int sd[256];
    int t = threadIdx.x;
    int base = blockIdx.x * 1024 + t * 4;
    int s = 0;
#pragma unroll
    for (int j = 0; j < 4; j++) { int i = base + j; if (i < n) s += cnt[i]; }
    sd[t] = s; __syncthreads();
    for (int off = 128; off > 0; off >>= 1) {
        if (t < off) sd[t] += sd[t + off];
        __syncthreads();
    }
    if (t == 0) csum[blockIdx.x] = sd[0];
}

// parallel exclusive scan over up to 256 chunk sums (NCHUNK=98 here), 1 block
__global__ void k_scanB(int* csum, int* offsets, int nchunk, int n) {
    __shared__ int sd[256];
    int t = threadIdx.x;
    int v = (t < nchunk) ? csum[t] : 0;
    sd[t] = v; __syncthreads();
    for (int off = 1; off < 256; off <<= 1) {
        int u = (t >= off) ? sd[t - off] : 0;
        __syncthreads();
        sd[t] += u;
        __syncthreads();
    }
    if (t < nchunk) csum[t] = sd[t] - v;   // exclusive prefix
    if (t == 0) offsets[n] = sd[255];      // total = E + N
}

// scanC + node_init fused: writes offsets, dinv, cursor, and the self-loop entry.
__global__ void k_scanC(const int* __restrict__ cnt, const int* __restrict__ csum,
                        int* offsets, int* cursor, float* dinv,
                        int* adj_src, float* adj_norm, int n) {
    __shared__ int sd[256];
    int t = threadIdx.x;
    int base = blockIdx.x * 1024 + t * 4;
    int c[4]; int s = 0;
#pragma unroll
    for (int j = 0; j < 4; j++) {
        c[j] = (base + j < n) ? cnt[base + j] : 0;
        s += c[j];
    }
    sd[t] = s; __syncthreads();
    for (int off = 1; off < 256; off <<= 1) {
        int v = (t >= off) ? sd[t - off] : 0;
        __syncthreads();
        sd[t] += v;
        __syncthreads();
    }
    int run = sd[t] - s + csum[blockIdx.x];  // exclusive prefix + chunk base
#pragma unroll
    for (int j = 0; j < 4; j++) {
        int i = base + j;
        if (i < n) {
            offsets[i] = run;
            float di = rsqrtf((float)c[j]);   // deg >= 1 (self-loop)
            dinv[i] = di;
            cursor[i] = run + 1;
            adj_src[run] = i;                 // self-loop entry first
            adj_norm[run] = di * di;
        }
        run += c[j];
    }
}

__global__ void k_fill_edges(const int* __restrict__ ei, int* cursor,
                             const float* __restrict__ dinv,
                             int* adj_src, float* adj_norm, int E) {
    int e = blockIdx.x * blockDim.x + threadIdx.x;
    if (e >= E) return;
    int s = ei[e];
    int d = ei[E + e];
    int pos = atomicAdd(&cursor[d], 1);
    adj_src[pos] = s;
    adj_norm[pos] = dinv[s] * dinv[d];
}

// pack W[l] (fp32 [k][n]) into transposed bf16 planes Whp/Wlp [n][k]
__global__ void k_packW(const float* __restrict__ Ws, ushort* Whp, ushort* Wlp,
                        int nlayers) {
    int idx = blockIdx.x * blockDim.x + threadIdx.x;      // l*16384 + n*128 + k
    if (idx >= nlayers * HID * HID) return;
    int l = idx >> 14;
    int n = (idx >> 7) & 127;
    int k = idx & 127;
    float w = Ws[(size_t)l * HID * HID + k * HID + n];
    __hip_bfloat16 hi = __float2bfloat16(w);
    float lo = w - __bfloat162float(hi);
    __hip_bfloat16 lo16 = __float2bfloat16(lo);
    Whp[idx] = *(ushort*)&hi;
    Wlp[idx] = *(ushort*)&lo16;
}

// ---------- per-layer: pull aggregation ----------
// One wave per node. Wave quarters: q>>1 = edge-slot parity, q&1 = feature half.
// Body = round-9 verified shape. Epilogue: split acc into bf16 hi/lo planes.

__global__ __launch_bounds__(256) void k_agg(const float* __restrict__ x,
                                             const int* __restrict__ offsets,
                                             const int* __restrict__ adj_src,
                                             const float* __restrict__ adj_norm,
                                             ushort* __restrict__ yh,
                                             ushort* __restrict__ yl, int n) {
    int gid = blockIdx.x * blockDim.x + threadIdx.x;
    int node = gid >> 6;
    int lane = gid & 63;
    if (node >= n) return;
    int beg = offsets[node];
    int end = offsets[node + 1];
    int q    = lane >> 4;            // quarter 0..3
    int ql   = lane & 15;
    int f4   = (q & 1) * 16 + ql;    // float4 index within row, [0,32)
    int epar = q >> 1;               // edge-slot parity 0/1
    float4 acc = {0.f, 0.f, 0.f, 0.f};
#pragma unroll 2
    for (int e = beg; e < end; e += 2) {
        int me = e + epar;
        int mc = me < end ? me : end - 1;          // clamp -> always-valid load
        int s  = adj_src[mc];                      // broadcast within quarter-pair
        float w = me < end ? adj_norm[mc] : 0.f;   // masked weight for odd tail
        float4 v = ((const float4*)(x + (size_t)s * HID))[f4];
        acc.x += w * v.x;
        acc.y += w * v.y;
        acc.z += w * v.z;
        acc.w += w * v.w;
    }
    acc.x += __shfl_xor(acc.x, 32);
    acc.y += __shfl_xor(acc.y, 32);
    acc.z += __shfl_xor(acc.z, 32);
    acc.w += __shfl_xor(acc.w, 32);
    if (lane < 32) {
        float a[4] = {acc.x, acc.y, acc.z, acc.w};
        ushort4 h, l;
        ushort* hp = (ushort*)&h;
        ushort* lp = (ushort*)&l;
#pragma unroll
        for (int j = 0; j < 4; j++) {
            __hip_bfloat16 hi = __float2bfloat16(a[j]);
            float lo = a[j] - __bfloat162float(hi);
            __hip_bfloat16 lo16 = __float2bfloat16(lo);
            hp[j] = *(ushort*)&hi;
            lp[j] = *(ushort*)&lo16;
        }
        ((ushort4*)(yh + (size_t)node * HID))[lane] = h;
        ((ushort4*)(yl + (size_t)node * HID))[lane] = l;
    }
}

// ---------- per-layer: GEMM via split-bf16 MFMA 16x16x32, W in LDS ----------
// Block 256 thr = 4 waves; tile 128 rows x 128 cols; wave w -> rows w*32..w*32+31
// (two 16-row m-tiles). W planes staged in LDS (padded rows, 68KB -> 2 blocks/CU).
// A frags (16 x 16B per lane) loaded up-front, in flight behind the staging barrier.
// Inner loop: 2 ds_read_b128 + 6 MFMA. C/D: col=lane&15, row=(lane>>4)*4+reg.

__global__ __launch_bounds__(256, 2) void k_gemm_mfma(const ushort* __restrict__ yh,
                                                      const ushort* __restrict__ yl,
                                                      const ushort* __restrict__ Whp,
                                                      const ushort* __restrict__ Wlp,
                                                      const float* __restrict__ bias,
                                                      float* __restrict__ out, int n) {
    __shared__ ushort Wh_lds[HID * WLDS];   // 34816 B
    __shared__ ushort Wl_lds[HID * WLDS];   // 34816 B
    int t = threadIdx.x;
    int wave = t >> 6;
    int lane = t & 63;
    int m16  = lane & 15;
    int oct  = lane >> 4;            // k-octet 0..3

    // A fragments up-front (independent 16B loads; overlap the W staging below)
    short8 ah[2][4], al[2][4];
#pragma unroll
    for (int mt = 0; mt < 2; mt++) {
        int rowA = blockIdx.x * 128 + wave * 32 + mt * 16 + m16;
        const ushort* hb = yh + (size_t)rowA * HID + oct * 8;
        const ushort* lb = yl + (size_t)rowA * HID + oct * 8;
#pragma unroll
        for (int ks = 0; ks < 4; ks++) {
            ah[mt][ks] = *(const short8*)(hb + ks * 32);
            al[mt][ks] = *(const short8*)(lb + ks * 32);
        }
    }

    // stage W planes: 128 rows x 16 uint4 per plane
    for (int idx = t; idx < HID * 16; idx += 256) {
        int r = idx >> 4, c8 = idx & 15;
        ((uint4*)(Wh_lds + r * WLDS))[c8] = ((const uint4*)(Whp + r * HID))[c8];
        ((uint4*)(Wl_lds + r * WLDS))[c8] = ((const uint4*)(Wlp + r * HID))[c8];
    }
    __syncthreads();

    floatx4 acc0[8], acc1[8];
#pragma unroll
    for (int c = 0; c < 8; c++) {
        acc0[c] = (floatx4){0.f, 0.f, 0.f, 0.f};
        acc1[c] = (floatx4){0.f, 0.f, 0.f, 0.f};
    }

#pragma unroll
    for (int ks = 0; ks < 4; ks++) {                    // K = 128 = 4 x 32
#pragma unroll
        for (int c = 0; c < 8; c++) {                   // 8 col-tiles of 16
            const ushort* bp = Wh_lds + (c * 16 + m16) * WLDS + ks * 32 + oct * 8;
            const ushort* bq = Wl_lds + (c * 16 + m16) * WLDS + ks * 32 + oct * 8;
            short8 bh = *(const short8*)bp;
            short8 bl = *(const short8*)bq;
            acc0[c] = __builtin_amdgcn_mfma_f32_16x16x32_bf16(ah[0][ks], bh, acc0[c], 0, 0, 0);
            acc0[c] = __builtin_amdgcn_mfma_f32_16x16x32_bf16(ah[0][ks], bl, acc0[c], 0, 0, 0);
            acc0[c] = __builtin_amdgcn_mfma_f32_16x16x32_bf16(al[0][ks], bh, acc0[c], 0, 0, 0);
            acc1[c] = __builtin_amdgcn_mfma_f32_16x16x32_bf16(ah[1][ks], bh, acc1[c], 0, 0, 0);
            acc1[c] = __builtin_amdgcn_mfma_f32_16x16x32_bf16(ah[1][ks], bl, acc1[c], 0, 0, 0);
            acc1[c] = __builtin_amdgcn_mfma_f32_16x16x32_bf16(al[1][ks], bh, acc1[c], 0, 0, 0);
        }
    }

    // epilogue: bias + relu + store (C/D: col=lane&15, row=(lane>>4)*4+reg)
#pragma unroll
    for (int mt = 0; mt < 2; mt++) {
        int rowbase = blockIdx.x * 128 + wave * 32 + mt * 16 + oct * 4;
#pragma unroll
        for (int c = 0; c < 8; c++) {
            int col = c * 16 + m16;
            float b = bias[col];
            floatx4 a = mt == 0 ? acc0[c] : acc1[c];
#pragma unroll
            for (int r = 0; r < 4; r++) {
                int row = rowbase + r;
                if (row < n) {
                    float v = fmaxf(a[r] + b, 0.f);
                    out[(size_t)row * HID + col] = v;
                }
            }
        }
    }
}

// ---------- launch ----------

extern "C" void kernel_launch(void* const* d_in, const int* in_sizes, int n_in,
                              void* d_out, int out_size, void* d_ws, size_t ws_size,
                              hipStream_t stream) {
    const int* ei = (const int*)d_in[0];          // (2, E) int32
    const float* emb = (const float*)d_in[1];     // (N, 128)
    const float* Ws = (const float*)d_in[2];      // (3, 128, 128)
    const float* bs = (const float*)d_in[3];      // (3, 128)

    const int E = in_sizes[0] / 2;                // 600000
    const int N = in_sizes[1] / HID;              // 100000
    const int NL = in_sizes[3] / HID;             // 3
    const int TOT = E + N;
    const int NPAD = ((N + 127) / 128) * 128;     // 100096 (A-loads unmasked)

    // workspace carve-up (256B aligned)
    char* p = (char*)d_ws;
    auto carve = [&](size_t bytes) {
        char* r = p;
        p += (bytes + 255) & ~(size_t)255;
        return (void*)r;
    };
    int*    cnt      = (int*)   carve((size_t)N * 4);
    int*    offsets  = (int*)   carve((size_t)(N + 1) * 4);
    int*    cursor   = (int*)   carve((size_t)N * 4);
    float*  dinv     = (float*) carve((size_t)N * 4);
    int*    csum     = (int*)   carve(1024 * 4);
    int*    adj_src  = (int*)   carve((size_t)TOT * 4);
    float*  adj_norm = (float*) carve((size_t)TOT * 4);
    ushort* yh       = (ushort*)carve((size_t)NPAD * HID * 2);
    ushort* yl       = (ushort*)carve((size_t)NPAD * HID * 2);
    ushort* Whp      = (ushort*)carve((size_t)NL * HID * HID * 2);
    ushort* Wlp      = (ushort*)carve((size_t)NL * HID * HID * 2);
    float*  xbufA    = (float*) carve((size_t)N * HID * 4);
    float*  xbufB    = (float*) d_out;    // l0 and l2 outputs land here

    const int NCHUNK = (N + 1023) / 1024;   // 98 <= 256 (scanB capacity)

    k_init_cnt<<<(N + 255) / 256, 256, 0, stream>>>(cnt, N);
    k_count_edges<<<(E + 255) / 256, 256, 0, stream>>>(ei, cnt, E);
    k_scanA<<<NCHUNK, 256, 0, stream>>>(cnt, csum, N);
    k_scanB<<<1, 256, 0, stream>>>(csum, offsets, NCHUNK, N);
    k_scanC<<<NCHUNK, 256, 0, stream>>>(cnt, csum, offsets, cursor, dinv,
                                        adj_src, adj_norm, N);
    k_fill_edges<<<(E + 255) / 256, 256, 0, stream>>>(ei, cursor, dinv,
                                                      adj_src, adj_norm, E);
    k_packW<<<(NL * HID * HID + 255) / 256, 256, 0, stream>>>(Ws, Whp, Wlp, NL);

    const int aggBlocks = (N * 64 + 255) / 256;
    const int gemmBlocks = NPAD / 128;    // 782
    // l0: emb -> d_out, l1: d_out -> xbufA, l2: xbufA -> d_out
    const float* x = emb;
    for (int l = 0; l < NL; l++) {
        float* o = (l == 1) ? xbufA : xbufB;
        k_agg<<<aggBlocks, 256, 0, stream>>>(x, offsets, adj_src, adj_norm, yh, yl, N);
        k_gemm_mfma<<<gemmBlocks, 256, 0, stream>>>(yh, yl,
                                                    Whp + (size_t)l * HID * HID,
                                                    Wlp + (size_t)l * HID * HID,
                                                    bs + (size_t)l * HID, o, N);
        x = o;
    }
}